// Round 11
// baseline (334.659 us; speedup 1.0000x reference)
//
#include <hip/hip_runtime.h>
#include <cstdint>

#define B_SZ 8192
#define IN_SZ 1024
#define H_SZ 1024

typedef unsigned short u16;
typedef __bf16 bf16_t;
typedef bf16_t bf16x8 __attribute__((ext_vector_type(8)));
typedef float floatx4 __attribute__((ext_vector_type(4)));

__device__ __forceinline__ u16 f2bf(float f) {
    unsigned int u = __float_as_uint(f);
    u += 0x7fffu + ((u >> 16) & 1u);   // RNE
    return (u16)(u >> 16);
}

__device__ __forceinline__ ushort4 cvt4(float4 v) {
    ushort4 o;
    o.x = f2bf(v.x); o.y = f2bf(v.y); o.z = f2bf(v.z); o.w = f2bf(v.w);
    return o;
}

// async global->LDS, 16B per lane; LDS dest = wave-uniform base + lane*16
__device__ __forceinline__ void g2l16(const u16* g, u16* l) {
    __builtin_amdgcn_global_load_lds(
        (__attribute__((address_space(1))) void*)(uintptr_t)g,
        (__attribute__((address_space(3))) void*)(uint32_t)(uintptr_t)l,
        16, 0, 0);
}

// phase boundary: pin order, counted vmcnt (NEVER 0 in steady state), raw barrier
template <int N>
__device__ __forceinline__ void phase_end() {
    __builtin_amdgcn_sched_barrier(0);
    if constexpr (N == 0) asm volatile("s_waitcnt vmcnt(0)" ::: "memory");
    else if constexpr (N == 4) asm volatile("s_waitcnt vmcnt(4)" ::: "memory");
    else if constexpr (N == 8) asm volatile("s_waitcnt vmcnt(8)" ::: "memory");
    __builtin_amdgcn_s_barrier();
    __builtin_amdgcn_sched_barrier(0);
}

// ---------------- fused fp32 -> bf16 conversion into K-concat layouts -----------
// GRID-STRIDE (2048 blocks x 11 iters): r10's 22528 one-shot trivial blocks were
// dispatch-bound (G11); long per-wave streams amortize launch/scheduling.
// Acat[8192][2048] = [bf16(input) | bf16(hidden)]
// Brz [2048][2048] = [[Wir|Whr],[Wiz|Whz]];  Bh [1024][2048] = [Wih|Whh]
__global__ __launch_bounds__(256) void cvt_all(
    const float* __restrict__ x, const float* __restrict__ h,
    const float* __restrict__ Wir, const float* __restrict__ Whr,
    const float* __restrict__ Wiz, const float* __restrict__ Whz,
    const float* __restrict__ Wih, const float* __restrict__ Whh,
    u16* __restrict__ Acat, u16* __restrict__ Brz, u16* __restrict__ Bh) {
    const int t = threadIdx.x;
    for (int b = blockIdx.x; b < 22528; b += gridDim.x) {
        if (b < 8192) {
            float4 v = ((const float4*)(x + (size_t)b * 1024))[t];
            ((ushort4*)(Acat + (size_t)b * 2048))[t] = cvt4(v);
        } else if (b < 16384) {
            const int m = b - 8192;
            float4 v = ((const float4*)(h + (size_t)m * 1024))[t];
            ((ushort4*)(Acat + (size_t)m * 2048 + 1024))[t] = cvt4(v);
        } else {
            const int wb = b - 16384;   // 0..6143
            const int w = wb >> 10;
            const int n = wb & 1023;
            const float* src;
            u16* dst;
            switch (w) {
                case 0: src = Wir; dst = Brz + (size_t)n * 2048;               break;
                case 1: src = Whr; dst = Brz + (size_t)n * 2048 + 1024;        break;
                case 2: src = Wiz; dst = Brz + (size_t)(n + 1024) * 2048;      break;
                case 3: src = Whz; dst = Brz + (size_t)(n + 1024) * 2048 + 1024; break;
                case 4: src = Wih; dst = Bh + (size_t)n * 2048;                break;
                default: src = Whh; dst = Bh + (size_t)n * 2048 + 1024;        break;
            }
            float4 v = ((const float4*)(src + (size_t)n * 1024))[t];
            ((ushort4*)dst)[t] = cvt4(v);
        }
    }
}

// ---------------- gemm_rz: r5/r10-EXACT 256x256 ring-4 + counted vmcnt + T2 -----
// Best-measured GEMM of the session (r10: 106.2-106.6us, ~650 TF, 0 conflicts).
// DO NOT MODIFY: every structural variant tried (2-phase dbuf, phase-split,
// reg-staged B, 128^2 ring-3, (256,3) floor) measured equal or worse (r1-r9).
__global__ __launch_bounds__(512) void gemm_rz(
    const u16* __restrict__ A0, const u16* __restrict__ A1,
    const u16* __restrict__ Bw,
    const float* __restrict__ bx0, const float* __restrict__ bh0,
    const float* __restrict__ bx1, const float* __restrict__ bh1,
    const float* __restrict__ hidden,
    u16* __restrict__ out_rh, float* __restrict__ out_zf) {
    constexpr int BM = 256, BN = 256, BK = 32, NKT = 64;   // K = 2048
    constexpr int PM = 128, PN = 64;                       // wave grid 2x4
    constexpr int FM = 8, FN = 4;
    constexpr int AG = 2, BG = 2, LS = AG + BG;            // 4

    __shared__ u16 As[4][BM * BK];          // 4 x 16 KB
    __shared__ u16 Bs[4][BN * BK];          // 4 x 16 KB

    const int tid = threadIdx.x;
    const int wave = tid >> 6;
    const int lane = tid & 63;
    // chunked XCD swizzle (nwg = 256)
    const int wid = blockIdx.x;
    const int swz = (wid & 7) * 32 + (wid >> 3);
    const int bn = swz & 7;
    const int bm = swz >> 3;
    const int wc = wave & 3;
    const int wr = wave >> 2;

    const floatx4 z4 = {0.f, 0.f, 0.f, 0.f};
    floatx4 acc[FM][FN];
#pragma unroll
    for (int i = 0; i < FM; ++i)
#pragma unroll
        for (int j = 0; j < FN; ++j) acc[i][j] = z4;

    // staging source coords (inverse swizzle on global address), rule #21
    int rowA[AG], gkA[AG], rowB[BG], gkB[BG];
#pragma unroll
    for (int j = 0; j < 2; ++j) {
        const int c = j * 512 + tid;
        const int sup = c >> 3;
        const int u = (c & 7) ^ (sup & 7);
        rowA[j] = sup * 2 + (u >> 2);  gkA[j] = (u & 3) * 8;
        rowB[j] = rowA[j];             gkB[j] = gkA[j];
    }

    // swizzled ds_read bases (u16 idx): frag i at base + i*512
    const int mr = lane & 15;
    const int sg = lane >> 4;               // k-slot 0..3
    const int R0 = wr * PM + mr;
    const int baseA = (R0 >> 1) * 64 + (((((R0 & 1) << 2) | sg) ^ ((R0 >> 1) & 7)) << 3);
    const int C0 = wc * PN + mr;
    const int baseB = (C0 >> 1) * 64 + (((((C0 & 1) << 2) | sg) ^ ((C0 >> 1) & 7)) << 3);

    auto stage = [&](int t) {
        const int buf = t & 3;
        const bool seg = t >= NKT / 2;
        const u16* __restrict__ Ab = seg ? A1 : A0;
        const int ka = (t & (NKT / 2 - 1)) * BK;
        const int kb = t * BK;
        u16* Asb = &As[buf][0];
        u16* Bsb = &Bs[buf][0];
#pragma unroll
        for (int j = 0; j < AG; ++j)
            g2l16(Ab + (size_t)(bm * BM + rowA[j]) * 2048 + ka + gkA[j],
                  Asb + (j * 512 + wave * 64) * 8);
#pragma unroll
        for (int j = 0; j < BG; ++j)
            g2l16(Bw + (size_t)(bn * BN + rowB[j]) * 2048 + kb + gkB[j],
                  Bsb + (j * 512 + wave * 64) * 8);
    };

    auto compute = [&](int t) {
        const u16* Asb = &As[t & 3][0];
        const u16* Bsb = &Bs[t & 3][0];
        bf16x8 af[FM], bv[FN];
#pragma unroll
        for (int i = 0; i < FM; ++i)
            af[i] = *(const bf16x8*)&Asb[baseA + i * 512];
#pragma unroll
        for (int j = 0; j < FN; ++j)
            bv[j] = *(const bf16x8*)&Bsb[baseB + j * 512];
        __builtin_amdgcn_s_setprio(1);
#pragma unroll
        for (int i = 0; i < FM; ++i)
#pragma unroll
            for (int j = 0; j < FN; ++j)
                acc[i][j] = __builtin_amdgcn_mfma_f32_16x16x32_bf16(
                    af[i], bv[j], acc[i][j], 0, 0, 0);
        __builtin_amdgcn_s_setprio(0);
    };

    // prologue: 3 tiles in flight
    stage(0); stage(1); stage(2);
    phase_end<2 * LS>();                 // S(0) resident
#pragma unroll 4
    for (int t = 0; t < NKT - 3; ++t) {  // t = 0..60
        stage(t + 3);
        compute(t);
        phase_end<2 * LS>();             // S(t+1) resident; t+2,t+3 in flight
    }
    compute(NKT - 3); phase_end<LS>();   // S(62) resident
    compute(NKT - 2); phase_end<0>();    // S(63) resident
    compute(NKT - 1);

    // epilogue: C/D layout col=lane&15, row=(lane>>4)*4+reg (m89/m91 verified)
    const int colBase = bn * BN + wc * PN + (lane & 15);
    const int rowBase = bm * BM + wr * PM + (lane >> 4) * 4;
    const bool is_r = (colBase < H_SZ);   // block-uniform (1024 % 256 == 0)
#pragma unroll
    for (int j = 0; j < FN; ++j) {
        const int coln = colBase + j * 16;
        const int cb = is_r ? coln : coln - H_SZ;
        const float bias = is_r ? (bx0[cb] + bh0[cb]) : (bx1[cb] + bh1[cb]);
#pragma unroll
        for (int i = 0; i < FM; ++i) {
#pragma unroll
            for (int r = 0; r < 4; ++r) {
                const int rown = rowBase + i * 16 + r;
                const size_t idx = (size_t)rown * H_SZ + cb;
                const float v = acc[i][j][r] + bias;
                const float s = 1.0f / (1.0f + __expf(-v));
                if (is_r) out_rh[idx] = f2bf(s * hidden[idx]);
                else      out_zf[idx] = s;
            }
        }
    }
}

// ---------------- gemm_h: r9/r10-style 128x128 ring-3, (256,3), 512 blocks ------
// h~ GEMM (N=1024, K=2048 = [X | r*h]): ht=tanh(C+b); out = z*h + (1-z)*ht.
__global__ __launch_bounds__(256, 3) void gemm_h(
    const u16* __restrict__ A0, const u16* __restrict__ A1,
    const u16* __restrict__ Bw,
    const float* __restrict__ bx0, const float* __restrict__ bh0,
    const float* __restrict__ hidden, const float* __restrict__ zbuf,
    float* __restrict__ out_f) {
    constexpr int BM = 128, BN = 128, BK = 32, NKT = 64;   // K = 2048
    constexpr int FM = 4, FN = 4, LS = 4, LNBN = 3;
    constexpr int SA0 = 2048, SA1 = 1024;

    __shared__ u16 As[3][BM * BK];         // 3 x 8 KB
    __shared__ u16 Bs[3][BN * BK];         // 3 x 8 KB

    const int tid = threadIdx.x;
    const int wave = tid >> 6;
    const int lane = tid & 63;
    const int nwg = gridDim.x;
    const int wid = blockIdx.x;
    const int swz = (wid & 7) * (nwg >> 3) + (wid >> 3);
    const int bn = swz & ((1 << LNBN) - 1);
    const int bm = swz >> LNBN;
    const int wr = wave >> 1, wc = wave & 1;   // 2x2 wave grid

    const floatx4 z4 = {0.f, 0.f, 0.f, 0.f};
    floatx4 acc[FM][FN];
#pragma unroll
    for (int i = 0; i < FM; ++i)
#pragma unroll
        for (int j = 0; j < FN; ++j) acc[i][j] = z4;

    int row[2], gk[2];
#pragma unroll
    for (int j = 0; j < 2; ++j) {
        const int c = j * 256 + tid;       // chunk 0..511
        const int sup = c >> 3;
        const int u = (c & 7) ^ (sup & 7);
        row[j] = sup * 2 + (u >> 2);
        gk[j] = (u & 3) * 8;
    }

    const int mr = lane & 15;
    const int sg = lane >> 4;
    const int R0 = wr * 64 + mr;
    const int baseA = (R0 >> 1) * 64 + (((((R0 & 1) << 2) | sg) ^ ((R0 >> 1) & 7)) << 3);
    const int C0 = wc * 64 + mr;
    const int baseB = (C0 >> 1) * 64 + (((((C0 & 1) << 2) | sg) ^ ((C0 >> 1) & 7)) << 3);

    auto stage = [&](int buf, int t) {
        const bool seg = t >= NKT / 2;
        const u16* __restrict__ Ab = seg ? A1 : A0;
        const int sA = seg ? SA1 : SA0;
        const int ka = (t & (NKT / 2 - 1)) * BK;
        const int kb = t * BK;
        u16* Asb = &As[buf][0];
        u16* Bsb = &Bs[buf][0];
#pragma unroll
        for (int j = 0; j < 2; ++j)
            g2l16(Ab + (size_t)(bm * BM + row[j]) * sA + ka + gk[j],
                  Asb + (j * 256 + wave * 64) * 8);
#pragma unroll
        for (int j = 0; j < 2; ++j)
            g2l16(Bw + (size_t)(bn * BN + row[j]) * 2048 + kb + gk[j],
                  Bsb + (j * 256 + wave * 64) * 8);
    };

    auto compute = [&](int buf) {
        const u16* Asb = &As[buf][0];
        const u16* Bsb = &Bs[buf][0];
        bf16x8 af[FM], bv[FN];
#pragma unroll
        for (int i = 0; i < FM; ++i)
            af[i] = *(const bf16x8*)&Asb[baseA + i * 512];
#pragma unroll
        for (int j = 0; j < FN; ++j)
            bv[j] = *(const bf16x8*)&Bsb[baseB + j * 512];
        __builtin_amdgcn_s_setprio(1);
#pragma unroll
        for (int i = 0; i < FM; ++i)
#pragma unroll
            for (int j = 0; j < FN; ++j)
                acc[i][j] = __builtin_amdgcn_mfma_f32_16x16x32_bf16(
                    af[i], bv[j], acc[i][j], 0, 0, 0);
        __builtin_amdgcn_s_setprio(0);
    };

    auto step = [&](int t, int bS, int bC) {
        stage(bS, t + 2);
        compute(bC);
        phase_end<LS>();
    };

    stage(0, 0); stage(1, 1);
    phase_end<LS>();
    for (int t = 0; t < 60; t += 3) {
        step(t, 2, 0); step(t + 1, 0, 1); step(t + 2, 1, 2);
    }
    step(60, 2, 0); step(61, 0, 1);
    compute(2);
    phase_end<0>();
    compute(0);

    const int colBase = bn * BN + wc * 64 + (lane & 15);
    const int rowBase = bm * BM + wr * 64 + (lane >> 4) * 4;
#pragma unroll
    for (int j = 0; j < FN; ++j) {
        const int coln = colBase + j * 16;
        const float bias = bx0[coln] + bh0[coln];
#pragma unroll
        for (int i = 0; i < FM; ++i) {
#pragma unroll
            for (int r = 0; r < 4; ++r) {
                const int rown = rowBase + i * 16 + r;
                const size_t idx = (size_t)rown * H_SZ + coln;
                const float v = acc[i][j][r] + bias;
                const float ht = tanhf(v);
                const float zz = zbuf[idx];
                const float hh = hidden[idx];
                out_f[idx] = zz * hh + (1.0f - zz) * ht;
            }
        }
    }
}

// ---------------- row-wise log_softmax over H=1024, 4 rows/block ----------------
// Grid-stride over rows (2048 blocks): r10's 8192 tiny one-row blocks were
// dispatch-bound. Cross-iteration LDS safety: redm/reds reads of row t happen
// before the barrier that the writer of row t+1's values must first pass.
__global__ __launch_bounds__(256) void lsm_kernel(const float* __restrict__ nh,
                                                  float* __restrict__ out) {
    const int tid = threadIdx.x;
    const int wave = tid >> 6, lane = tid & 63;
    __shared__ float redm[4];
    __shared__ float reds[4];
    for (int row = blockIdx.x; row < B_SZ; row += gridDim.x) {
        const float4 v = ((const float4*)(nh + (size_t)row * H_SZ))[tid];
        float m = fmaxf(fmaxf(v.x, v.y), fmaxf(v.z, v.w));
#pragma unroll
        for (int o = 32; o; o >>= 1) m = fmaxf(m, __shfl_xor(m, o));
        if (lane == 0) redm[wave] = m;
        __syncthreads();
        const float M = fmaxf(fmaxf(redm[0], redm[1]), fmaxf(redm[2], redm[3]));
        float s = __expf(v.x - M) + __expf(v.y - M) + __expf(v.z - M) + __expf(v.w - M);
#pragma unroll
        for (int o = 32; o; o >>= 1) s += __shfl_xor(s, o);
        if (lane == 0) reds[wave] = s;
        __syncthreads();
        const float S = reds[0] + reds[1] + reds[2] + reds[3];
        const float lse = M + __logf(S);
        float4 ov;
        ov.x = v.x - lse; ov.y = v.y - lse; ov.z = v.z - lse; ov.w = v.w - lse;
        ((float4*)(out + (size_t)row * H_SZ))[tid] = ov;
    }
}

extern "C" void kernel_launch(void* const* d_in, const int* in_sizes, int n_in,
                              void* d_out, int out_size, void* d_ws, size_t ws_size,
                              hipStream_t stream) {
    const float* input  = (const float*)d_in[0];
    const float* hidden = (const float*)d_in[1];
    const float* Wir = (const float*)d_in[2];  const float* bir = (const float*)d_in[3];
    const float* Whr = (const float*)d_in[4];  const float* bhr = (const float*)d_in[5];
    const float* Wiz = (const float*)d_in[6];  const float* biz = (const float*)d_in[7];
    const float* Whz = (const float*)d_in[8];  const float* bhz = (const float*)d_in[9];
    const float* Wih = (const float*)d_in[10]; const float* bih = (const float*)d_in[11];
    const float* Whh = (const float*)d_in[12]; const float* bhh = (const float*)d_in[13];

    // workspace layout (92 MB total)
    char* ws = (char*)d_ws;
    u16* Acat = (u16*)(ws);                     // 32 MB  [8192][2048] = [X | H]
    u16* Brz  = (u16*)(ws + (32u << 20));       //  8 MB  [2048][2048]
    u16* Bh   = (u16*)(ws + (40u << 20));       //  4 MB  [1024][2048]
    u16* RHb  = (u16*)(ws + (44u << 20));       // 16 MB  [8192][1024] r*hidden bf16
    float* Zf = (float*)(ws + (60u << 20));     // 32 MB  z f32

    float* out_lsm = (float*)d_out;
    float* out_nh  = (float*)d_out + (size_t)B_SZ * H_SZ;

    cvt_all<<<2048, 256, 0, stream>>>(
        input, hidden, Wir, Whr, Wiz, Whz, Wih, Whh, Acat, Brz, Bh);

    // fused r+z GEMM: M=8192 N=2048 K=2048, 256x256 tiles -> 256 blocks (r10-exact)
    gemm_rz<<<256, 512, 0, stream>>>(
        Acat, Acat + 1024, Brz, bir, bhr, biz, bhz, hidden, RHb, Zf);
    // h~ GEMM: M=8192 N=1024 K=2048 (X | RHb), 128x128 tiles -> 512 blocks
    gemm_h<<<512, 256, 0, stream>>>(
        Acat, RHb, Bh, bih, bhh, hidden, Zf, out_nh);

    lsm_kernel<<<2048, 256, 0, stream>>>(out_nh, out_lsm);
}